// Round 16
// baseline (317.038 us; speedup 1.0000x reference)
//
#include <hip/hip_runtime.h>
#include <hip/hip_fp16.h>
#include <math.h>

#define NN 100000
#define NE 3200000
#define INF_ 128
#define D 32
#define H 4
#define HD 8

// binning config: bucket = dst >> 8 (256 dst nodes per bucket)
#define BSH 8
#define BNODES 256
#define NBKT 391                // ceil(100000/256)
#define NBLK 512                // chunking blocks for pass C
#define EPB (NE / NBLK)         // 6250 edges per block
#define CAP 12288               // LDS sorted capacity
#define RCAP 9216               // fixed region capacity (mean 8192, +11 sigma)
#define DGRID 391               // node-per-thread dense grid (391*256 >= NN)

typedef _Float16 f16;
typedef f16 __attribute__((ext_vector_type(2))) f16x2;
typedef f16 __attribute__((ext_vector_type(8))) f16x8v;

__device__ __forceinline__ float gelu_f(float x) {
    return 0.5f * x * (1.0f + erff(x * 0.70710678118654752f));
}

// qv layout: qv[pair][node][32] halves = {q_h0[8], q_h1[8], v_h0[8], v_h1[8]} (64B row)
// kh layout: kh[pair][node][16] halves = {k_h0[8], k_h1[8]} (32B row)

// layer0 fused, node-per-thread: activations in registers, weights broadcast
// from LDS (1 ds_read per fdot2, wave-uniform address). Fully unrolled.
__global__ __launch_bounds__(256) void k_in_proj_qkv(const float* __restrict__ x,
        const float* __restrict__ W, const float* __restrict__ b,
        const float* __restrict__ Wq, const float* __restrict__ bq,
        const float* __restrict__ Wk, const float* __restrict__ bk,
        const float* __restrict__ Wv, const float* __restrict__ bv,
        float* __restrict__ h, __half* __restrict__ qv, __half* __restrict__ kh,
        int* __restrict__ cur) {
    __shared__ f16x2 Ws2[64 * D];      // 8 KB
    __shared__ f16x2 Wqkv2[3 * 16 * D];// 6 KB
    __shared__ float bias_s[4 * D];
    if (blockIdx.x == 0) {
        for (int i = threadIdx.x; i < NBKT; i += 256) cur[i] = 0;
    }
    for (int idx = threadIdx.x; idx < 64 * D; idx += 256) {
        int i2 = idx >> 5, c = idx & 31;
        Ws2[idx] = f16x2{(f16)W[(2 * i2) * D + c], (f16)W[(2 * i2 + 1) * D + c]};
    }
    for (int idx = threadIdx.x; idx < 16 * D; idx += 256) {
        int i2 = idx >> 5, c = idx & 31;
        Wqkv2[idx]        = f16x2{(f16)Wq[(2 * i2) * D + c], (f16)Wq[(2 * i2 + 1) * D + c]};
        Wqkv2[512 + idx]  = f16x2{(f16)Wk[(2 * i2) * D + c], (f16)Wk[(2 * i2 + 1) * D + c]};
        Wqkv2[1024 + idx] = f16x2{(f16)Wv[(2 * i2) * D + c], (f16)Wv[(2 * i2 + 1) * D + c]};
    }
    if (threadIdx.x < D) {
        bias_s[threadIdx.x]         = b[threadIdx.x];
        bias_s[D + threadIdx.x]     = bq[threadIdx.x];
        bias_s[2 * D + threadIdx.x] = bk[threadIdx.x];
        bias_s[3 * D + threadIdx.x] = bv[threadIdx.x];
    }
    __syncthreads();
    int node = blockIdx.x * 256 + threadIdx.x;
    if (node >= NN) return;
    f16x2 xr[64];
    const float4* xp = (const float4*)(x + (size_t)node * INF_);
    #pragma unroll
    for (int i = 0; i < 32; ++i) {
        float4 v = xp[i];
        xr[2 * i]     = f16x2{(f16)v.x, (f16)v.y};
        xr[2 * i + 1] = f16x2{(f16)v.z, (f16)v.w};
    }
    f16x2 hp16[16];
    float hf[32];
    #pragma unroll
    for (int col = 0; col < D; ++col) {
        float acc = bias_s[col];
        #pragma unroll
        for (int i2 = 0; i2 < 64; ++i2)
            acc = __builtin_amdgcn_fdot2(xr[i2], Ws2[i2 * D + col], acc, false);
        float hv = gelu_f(acc);
        hf[col] = hv;
        hp16[col >> 1][col & 1] = (f16)hv;
    }
    float4* hrow = (float4*)(h + (size_t)node * D);
    #pragma unroll
    for (int i = 0; i < 8; ++i) {
        float4 t;
        t.x = hf[4 * i]; t.y = hf[4 * i + 1]; t.z = hf[4 * i + 2]; t.w = hf[4 * i + 3];
        hrow[i] = t;
    }
    f16x8v Q8[4], K8[4], V8[4];
    #pragma unroll
    for (int col = 0; col < D; ++col) {
        float aq = bias_s[D + col], ak = bias_s[2 * D + col], av = bias_s[3 * D + col];
        #pragma unroll
        for (int i2 = 0; i2 < 16; ++i2) {
            f16x2 hx = hp16[i2];
            aq = __builtin_amdgcn_fdot2(hx, Wqkv2[i2 * D + col], aq, false);
            ak = __builtin_amdgcn_fdot2(hx, Wqkv2[512 + i2 * D + col], ak, false);
            av = __builtin_amdgcn_fdot2(hx, Wqkv2[1024 + i2 * D + col], av, false);
        }
        Q8[col >> 3][col & 7] = (f16)aq;
        K8[col >> 3][col & 7] = (f16)ak;
        V8[col >> 3][col & 7] = (f16)av;
    }
    f16x8v* q0 = (f16x8v*)(qv + (size_t)node * 32);
    q0[0] = Q8[0]; q0[1] = Q8[1]; q0[2] = V8[0]; q0[3] = V8[1];
    f16x8v* q1 = (f16x8v*)(qv + ((size_t)NN + node) * 32);
    q1[0] = Q8[2]; q1[1] = Q8[3]; q1[2] = V8[2]; q1[3] = V8[3];
    f16x8v* k0 = (f16x8v*)(kh + (size_t)node * 16);
    k0[0] = K8[0]; k0[1] = K8[1];
    f16x8v* k1 = (f16x8v*)(kh + ((size_t)NN + node) * 16);
    k1[0] = K8[2]; k1[1] = K8[3];
}

// pass C: LDS-staged bucket scatter; bkt16[pos] replaces per-edge binary search.
__global__ __launch_bounds__(256) void k_binC(const int* __restrict__ src,
        const int* __restrict__ dst, int* __restrict__ cur,
        unsigned int* __restrict__ tmp) {
    __shared__ int hist[NBKT];
    __shared__ int sc[512];
    __shared__ int gadj[NBKT];
    __shared__ unsigned int stage[EPB];        // 25 KB
    __shared__ unsigned short bkt16[EPB];      // 12.5 KB
    for (int i = threadIdx.x; i < NBKT; i += 256) hist[i] = 0;
    __syncthreads();
    int base = blockIdx.x * EPB;
    for (int i = threadIdx.x; i < EPB; i += 256)
        atomicAdd(&hist[dst[base + i] >> BSH], 1);
    __syncthreads();
    int t = threadIdx.x;
    sc[t]       = (t < NBKT) ? hist[t] : 0;
    sc[t + 256] = (t + 256 < NBKT) ? hist[t + 256] : 0;
    __syncthreads();
    for (int off = 1; off < 512; off <<= 1) {
        int a = (t >= off) ? sc[t - off] : 0;
        int b2 = sc[t + 256 - off];
        __syncthreads();
        sc[t] += a;
        sc[t + 256] += b2;
        __syncthreads();
    }
    for (int i = threadIdx.x; i < NBKT; i += 256) {
        int c = hist[i];
        int lb = sc[i] - c;
        hist[i] = lb;                          // placement cursor
        gadj[i] = c ? (atomicAdd(&cur[i], c) + i * RCAP - lb) : 0;
    }
    __syncthreads();
    for (int i = threadIdx.x; i < EPB; i += 256) {
        int d = dst[base + i];
        int bkt = d >> BSH;
        int pos = atomicAdd(&hist[bkt], 1);
        stage[pos] = (unsigned int)src[base + i]
                   | ((unsigned int)(d & (BNODES - 1)) << 17);
        bkt16[pos] = (unsigned short)bkt;
    }
    __syncthreads();
    for (int i = threadIdx.x; i < EPB; i += 256)
        tmp[gadj[bkt16[i]] + i] = stage[i];
}

// pass D: per-bucket LDS counting sort; emits rs/deg; streams full lines to csr.
__global__ __launch_bounds__(256) void k_binD(const unsigned int* __restrict__ tmp,
        const int* __restrict__ cur, int* __restrict__ csr,
        int* __restrict__ rs, int* __restrict__ deg) {
    __shared__ int lcnt[BNODES];
    __shared__ int lscan[BNODES];
    __shared__ int sorted[CAP];
    int b = blockIdx.x;
    int s0 = b * RCAP;
    int len = min(cur[b], RCAP);
    int s1 = s0 + len;
    lcnt[threadIdx.x] = 0;
    __syncthreads();
    for (int i = s0 + threadIdx.x; i < s1; i += 256)
        atomicAdd(&lcnt[tmp[i] >> 17], 1);
    __syncthreads();
    int v = lcnt[threadIdx.x];
    lscan[threadIdx.x] = v;
    __syncthreads();
    for (int off = 1; off < BNODES; off <<= 1) {
        int t = (threadIdx.x >= off) ? lscan[threadIdx.x - off] : 0;
        __syncthreads();
        lscan[threadIdx.x] += t;
        __syncthreads();
    }
    int excl = lscan[threadIdx.x] - v;
    int node = (b << BSH) + threadIdx.x;
    if (node < NN) {
        rs[node] = s0 + excl;
        deg[node] = v;
    }
    lcnt[threadIdx.x] = excl;
    __syncthreads();
    for (int i = s0 + threadIdx.x; i < s1; i += 256) {
        unsigned int p = tmp[i];
        int pos = atomicAdd(&lcnt[p >> 17], 1);
        sorted[pos] = (int)(p & 0x1FFFFu);
    }
    __syncthreads();
    for (int j = threadIdx.x; j < len; j += 256)
        csr[s0 + j] = sorted[j];
}

// attention (unchanged from R12): block = one head-PAIR x 8 nodes.
__global__ __launch_bounds__(256) void k_attn(const __half* __restrict__ qv,
        const __half* __restrict__ kh,
        const int* __restrict__ rs, const int* __restrict__ deg,
        const int* __restrict__ csr, float* __restrict__ attnh) {
    int b = blockIdx.x;
    int pair = (b & 7) >> 2;
    int j = (b >> 3) * 4 + (b & 3);
    int lane = threadIdx.x & 63;
    int half = lane >> 5;
    int l5 = lane & 31;
    int slot = l5 >> 1, hp = l5 & 1;
    int node = j * 8 + (threadIdx.x >> 6) * 2 + half;
    const __half* qvb = qv + (size_t)pair * NN * 32;
    union HF { float4 f4; __half2 h2[4]; };
    HF ku;
    ku.f4 = *(const float4*)(kh + ((size_t)pair * NN + node) * 16 + hp * 8);
    float kf[HD];
    #pragma unroll
    for (int i = 0; i < 4; ++i) {
        float2 t = __half22float2(ku.h2[i]);
        kf[2 * i] = t.x; kf[2 * i + 1] = t.y;
    }
    int start = rs[node], g = deg[node];
    int C = (g + 15) >> 4;
    int Cw = max(C, __shfl_xor(C, 32));
    float l = 0.f;
    float acc[HD];
    #pragma unroll
    for (int i = 0; i < HD; ++i) acc[i] = 0.f;

    bool act = slot < g;
    HF qu, vu;
    if (act) {
        int sn = csr[start + slot];
        const __half* r = qvb + (size_t)sn * 32;
        qu.f4 = *(const float4*)(r + hp * 8);
        vu.f4 = *(const float4*)(r + 16 + hp * 8);
    }
    for (int c = 1; c < Cw; ++c) {
        int idx2 = c * 16 + slot;
        bool act2 = idx2 < g;
        HF qu2, vu2;
        if (act2) {
            int sn2 = csr[start + idx2];
            const __half* r2 = qvb + (size_t)sn2 * 32;
            qu2.f4 = *(const float4*)(r2 + hp * 8);
            vu2.f4 = *(const float4*)(r2 + 16 + hp * 8);
        }
        if (act) {
            float s = 0.f;
            #pragma unroll
            for (int i = 0; i < 4; ++i) {
                float2 t = __half22float2(qu.h2[i]);
                s = fmaf(t.x, kf[2 * i], s);
                s = fmaf(t.y, kf[2 * i + 1], s);
            }
            float p = __expf(s * 0.35355339059327376f);
            l += p;
            #pragma unroll
            for (int i = 0; i < 4; ++i) {
                float2 t = __half22float2(vu.h2[i]);
                acc[2 * i] = fmaf(p, t.x, acc[2 * i]);
                acc[2 * i + 1] = fmaf(p, t.y, acc[2 * i + 1]);
            }
        }
        act = act2; qu = qu2; vu = vu2;
    }
    if (act) {
        float s = 0.f;
        #pragma unroll
        for (int i = 0; i < 4; ++i) {
            float2 t = __half22float2(qu.h2[i]);
            s = fmaf(t.x, kf[2 * i], s);
            s = fmaf(t.y, kf[2 * i + 1], s);
        }
        float p = __expf(s * 0.35355339059327376f);
        l += p;
        #pragma unroll
        for (int i = 0; i < 4; ++i) {
            float2 t = __half22float2(vu.h2[i]);
            acc[2 * i] = fmaf(p, t.x, acc[2 * i]);
            acc[2 * i + 1] = fmaf(p, t.y, acc[2 * i + 1]);
        }
    }
    #pragma unroll
    for (int off = 2; off < 32; off <<= 1) {
        l += __shfl_xor(l, off);
        #pragma unroll
        for (int i = 0; i < HD; ++i) acc[i] += __shfl_xor(acc[i], off);
    }
    if (slot == 0) {
        float inv = (l > 0.f) ? 1.0f / l : 0.f;
        float* outp = attnh + (size_t)node * D + (pair * 2 + hp) * HD;
        float4 o0 = { acc[0] * inv, acc[1] * inv, acc[2] * inv, acc[3] * inv };
        float4 o1 = { acc[4] * inv, acc[5] * inv, acc[6] * inv, acc[7] * inv };
        *(float4*)outp = o0;
        *(float4*)(outp + 4) = o1;
    }
}

// fused post-block, node-per-thread (activations in regs, weights broadcast).
__global__ __launch_bounds__(256) void k_post(const float* __restrict__ attnh,
        const float* __restrict__ Wo, const float* __restrict__ bo,
        const float* __restrict__ W1, const float* __restrict__ b1,
        const float* __restrict__ W2, const float* __restrict__ b2,
        float* __restrict__ h,
        const float* __restrict__ Wqn, const float* __restrict__ bqn,
        const float* __restrict__ Wkn, const float* __restrict__ bkn,
        const float* __restrict__ Wvn, const float* __restrict__ bvn,
        __half* __restrict__ qv, __half* __restrict__ kh,
        const float* __restrict__ W_out, const float* __restrict__ b_out,
        float* __restrict__ outp) {
    __shared__ f16x2 Wos2[16 * D], W1s2[16 * D], W2s2[16 * D];  // 2 KB each
    __shared__ f16x2 Wqkv2[3 * 16 * D];                         // 6 KB
    __shared__ float bias_s[6 * D];
    __shared__ float Wouts[D * 2 + 2];
    for (int idx = threadIdx.x; idx < 16 * D; idx += 256) {
        int i2 = idx >> 5, c = idx & 31;
        Wos2[idx] = f16x2{(f16)Wo[(2 * i2) * D + c], (f16)Wo[(2 * i2 + 1) * D + c]};
        W1s2[idx] = f16x2{(f16)W1[(2 * i2) * D + c], (f16)W1[(2 * i2 + 1) * D + c]};
        W2s2[idx] = f16x2{(f16)W2[(2 * i2) * D + c], (f16)W2[(2 * i2 + 1) * D + c]};
        if (Wqn) {
            Wqkv2[idx]        = f16x2{(f16)Wqn[(2 * i2) * D + c], (f16)Wqn[(2 * i2 + 1) * D + c]};
            Wqkv2[512 + idx]  = f16x2{(f16)Wkn[(2 * i2) * D + c], (f16)Wkn[(2 * i2 + 1) * D + c]};
            Wqkv2[1024 + idx] = f16x2{(f16)Wvn[(2 * i2) * D + c], (f16)Wvn[(2 * i2 + 1) * D + c]};
        }
    }
    if (threadIdx.x < D) {
        bias_s[threadIdx.x]         = bo[threadIdx.x];
        bias_s[D + threadIdx.x]     = b1[threadIdx.x];
        bias_s[2 * D + threadIdx.x] = b2[threadIdx.x];
        if (Wqn) {
            bias_s[3 * D + threadIdx.x] = bqn[threadIdx.x];
            bias_s[4 * D + threadIdx.x] = bkn[threadIdx.x];
            bias_s[5 * D + threadIdx.x] = bvn[threadIdx.x];
        }
    }
    if (outp && threadIdx.x < D * 2) Wouts[threadIdx.x] = W_out[threadIdx.x];
    if (outp && threadIdx.x < 2) Wouts[D * 2 + threadIdx.x] = b_out[threadIdx.x];
    __syncthreads();
    int node = blockIdx.x * 256 + threadIdx.x;
    if (node >= NN) return;
    f16x2 arp[16];
    const float4* ap = (const float4*)(attnh + (size_t)node * D);
    #pragma unroll
    for (int i = 0; i < 8; ++i) {
        float4 v = ap[i];
        arp[2 * i]     = f16x2{(f16)v.x, (f16)v.y};
        arp[2 * i + 1] = f16x2{(f16)v.z, (f16)v.w};
    }
    float hv[32];
    const float4* hp4 = (const float4*)(h + (size_t)node * D);
    #pragma unroll
    for (int i = 0; i < 8; ++i) {
        float4 v = hp4[i];
        hv[4 * i] = v.x; hv[4 * i + 1] = v.y; hv[4 * i + 2] = v.z; hv[4 * i + 3] = v.w;
    }
    f16x2 h1p[16];
    #pragma unroll
    for (int col = 0; col < D; ++col) {
        float a = bias_s[col];
        #pragma unroll
        for (int i2 = 0; i2 < 16; ++i2)
            a = __builtin_amdgcn_fdot2(arp[i2], Wos2[i2 * D + col], a, false);
        float h1 = hv[col] + a;
        hv[col] = h1;
        h1p[col >> 1][col & 1] = (f16)h1;
    }
    f16x2 tp[16];
    #pragma unroll
    for (int col = 0; col < D; ++col) {
        float t = bias_s[D + col];
        #pragma unroll
        for (int i2 = 0; i2 < 16; ++i2)
            t = __builtin_amdgcn_fdot2(h1p[i2], W1s2[i2 * D + col], t, false);
        tp[col >> 1][col & 1] = (f16)gelu_f(t);
    }
    f16x2 hnp[16];
    #pragma unroll
    for (int col = 0; col < D; ++col) {
        float o = bias_s[2 * D + col];
        #pragma unroll
        for (int i2 = 0; i2 < 16; ++i2)
            o = __builtin_amdgcn_fdot2(tp[i2], W2s2[i2 * D + col], o, false);
        float hn = hv[col] + o;
        hv[col] = hn;
        hnp[col >> 1][col & 1] = (f16)hn;
    }
    if (Wqn) {
        float4* hrow = (float4*)(h + (size_t)node * D);
        #pragma unroll
        for (int i = 0; i < 8; ++i) {
            float4 t;
            t.x = hv[4 * i]; t.y = hv[4 * i + 1]; t.z = hv[4 * i + 2]; t.w = hv[4 * i + 3];
            hrow[i] = t;
        }
        f16x8v Q8[4], K8[4], V8[4];
        #pragma unroll
        for (int col = 0; col < D; ++col) {
            float aq = bias_s[3 * D + col], ak = bias_s[4 * D + col], av = bias_s[5 * D + col];
            #pragma unroll
            for (int i2 = 0; i2 < 16; ++i2) {
                f16x2 hx = hnp[i2];
                aq = __builtin_amdgcn_fdot2(hx, Wqkv2[i2 * D + col], aq, false);
                ak = __builtin_amdgcn_fdot2(hx, Wqkv2[512 + i2 * D + col], ak, false);
                av = __builtin_amdgcn_fdot2(hx, Wqkv2[1024 + i2 * D + col], av, false);
            }
            Q8[col >> 3][col & 7] = (f16)aq;
            K8[col >> 3][col & 7] = (f16)ak;
            V8[col >> 3][col & 7] = (f16)av;
        }
        f16x8v* q0 = (f16x8v*)(qv + (size_t)node * 32);
        q0[0] = Q8[0]; q0[1] = Q8[1]; q0[2] = V8[0]; q0[3] = V8[1];
        f16x8v* q1 = (f16x8v*)(qv + ((size_t)NN + node) * 32);
        q1[0] = Q8[2]; q1[1] = Q8[3]; q1[2] = V8[2]; q1[3] = V8[3];
        f16x8v* k0 = (f16x8v*)(kh + (size_t)node * 16);
        k0[0] = K8[0]; k0[1] = K8[1];
        f16x8v* k1 = (f16x8v*)(kh + ((size_t)NN + node) * 16);
        k1[0] = K8[2]; k1[1] = K8[3];
    }
    if (outp) {
        float s0 = Wouts[D * 2], s1 = Wouts[D * 2 + 1];
        #pragma unroll
        for (int i = 0; i < D; ++i) {
            s0 = fmaf(hv[i], Wouts[i * 2], s0);
            s1 = fmaf(hv[i], Wouts[i * 2 + 1], s1);
        }
        float2 o = { s0, s1 };
        *(float2*)(outp + (size_t)node * 2) = o;
    }
}

extern "C" void kernel_launch(void* const* d_in, const int* in_sizes, int n_in,
                              void* d_out, int out_size, void* d_ws, size_t ws_size,
                              hipStream_t stream) {
    const float* x     = (const float*)d_in[0];
    const int*   src   = (const int*)d_in[1];
    const int*   dst   = (const int*)d_in[2];
    const float* W_in  = (const float*)d_in[3];
    const float* b_in  = (const float*)d_in[4];
    const float* Wq    = (const float*)d_in[5];
    const float* bq    = (const float*)d_in[6];
    const float* Wk    = (const float*)d_in[7];
    const float* bk    = (const float*)d_in[8];
    const float* Wv    = (const float*)d_in[9];
    const float* bv    = (const float*)d_in[10];
    const float* Wo    = (const float*)d_in[11];
    const float* bo    = (const float*)d_in[12];
    const float* W1    = (const float*)d_in[13];
    const float* b1    = (const float*)d_in[14];
    const float* W2    = (const float*)d_in[15];
    const float* b2    = (const float*)d_in[16];
    const float* W_out = (const float*)d_in[17];
    const float* b_out = (const float*)d_in[18];
    float* out = (float*)d_out;

    char* w = (char*)d_ws;
    size_t off = 0;
    auto alloc = [&](size_t bytes) -> void* {
        void* p = w + off;
        off += (bytes + 255) & ~(size_t)255;
        return p;
    };
    float*  h     = (float*)alloc((size_t)NN * D * 4);
    __half* qv    = (__half*)alloc((size_t)NN * 2 * 32 * 2);  // 2 pairs x 32 halves
    __half* kh    = (__half*)alloc((size_t)NN * 2 * 16 * 2);  // 2 pairs x 16 halves
    float*  attnh = (float*)alloc((size_t)NN * D * 4);
    int* deg    = (int*)alloc((size_t)NN * 4);
    int* rs     = (int*)alloc((size_t)NN * 4);
    int* cur    = (int*)alloc((size_t)NBKT * 4);
    unsigned int* tmp = (unsigned int*)alloc((size_t)(NBKT + 1) * RCAP * 4);
    int* csr    = (int*)alloc((size_t)(NBKT + 1) * RCAP * 4);
    (void)ws_size; (void)in_sizes; (void)n_in; (void)out_size;

    k_in_proj_qkv<<<DGRID, 256, 0, stream>>>(x, W_in, b_in,
            Wq, bq, Wk, bk, Wv, bv, h, qv, kh, cur);
    k_binC<<<NBLK, 256, 0, stream>>>(src, dst, cur, tmp);
    k_binD<<<NBKT, 256, 0, stream>>>(tmp, cur, csr, rs, deg);

    // layer 0: attn + post (post also emits layer-1 q/k/v)
    k_attn<<<NN / 8 * 2, 256, 0, stream>>>(qv, kh, rs, deg, csr, attnh);
    k_post<<<DGRID, 256, 0, stream>>>(attnh, Wo, bo, W1, b1, W2, b2, h,
            Wq + D * D, bq + D, Wk + D * D, bk + D, Wv + D * D, bv + D,
            qv, kh, nullptr, nullptr, nullptr);
    // layer 1: attn + post (post emits final out)
    k_attn<<<NN / 8 * 2, 256, 0, stream>>>(qv, kh, rs, deg, csr, attnh);
    k_post<<<DGRID, 256, 0, stream>>>(attnh, Wo + D * D, bo + D,
            W1 + D * D, b1 + D, W2 + D * D, b2 + D, h,
            nullptr, nullptr, nullptr, nullptr, nullptr, nullptr,
            nullptr, nullptr, W_out, b_out, out);
}

// Round 17
// 275.162 us; speedup vs baseline: 1.1522x; 1.1522x over previous
//
#include <hip/hip_runtime.h>
#include <hip/hip_fp16.h>
#include <math.h>

#define NN 100000
#define NE 3200000
#define INF_ 128
#define D 32
#define H 4
#define HD 8

// binning config: bucket = dst >> 8 (256 dst nodes per bucket)
#define BSH 8
#define BNODES 256
#define NBKT 391                // ceil(100000/256)
#define NBLK 512                // chunking blocks for pass C
#define EPB (NE / NBLK)         // 6250 edges per block
#define CAP 12288               // LDS sorted capacity
#define RCAP 9216               // fixed region capacity (mean 8192, +11 sigma)
#define NTILE (NN / 8)          // 12500 node tiles of 8
#define GS_GRID 1250            // grid-stride blocks (10 tiles each)

typedef _Float16 f16;
typedef f16 __attribute__((ext_vector_type(2))) f16x2;

__device__ __forceinline__ float gelu_f(float x) {
    return 0.5f * x * (1.0f + erff(x * 0.70710678118654752f));
}

// qv layout: qv[pair][node][32] halves = {q_h0[8], q_h1[8], v_h0[8], v_h1[8]} (64B row)
// kh layout: kh[pair][node][16] halves = {k_h0[8], k_h1[8]} (32B row)

// layer0 fused: h = gelu(x @ W_in + b_in); q/k/v = h @ Wqkv + b (fp16 pair-packed).
__global__ __launch_bounds__(256) void k_in_proj_qkv(const float* __restrict__ x,
        const float* __restrict__ W, const float* __restrict__ b,
        const float* __restrict__ Wq, const float* __restrict__ bq,
        const float* __restrict__ Wk, const float* __restrict__ bk,
        const float* __restrict__ Wv, const float* __restrict__ bv,
        float* __restrict__ h, __half* __restrict__ qv, __half* __restrict__ kh,
        int* __restrict__ cur) {
    __shared__ f16x2 Ws2[64 * D];      // 8 KB
    __shared__ f16x2 Wqkv2[3 * 16 * D];// 6 KB
    __shared__ f16 xs[8][INF_];        // 2 KB
    __shared__ f16 hsv[8][D];          // 0.5 KB
    if (blockIdx.x == 0) {
        for (int i = threadIdx.x; i < NBKT; i += 256) cur[i] = 0;
    }
    for (int idx = threadIdx.x; idx < 64 * D; idx += 256) {
        int i2 = idx >> 5, c = idx & 31;
        Ws2[idx] = f16x2{(f16)W[(2 * i2) * D + c], (f16)W[(2 * i2 + 1) * D + c]};
    }
    for (int idx = threadIdx.x; idx < 16 * D; idx += 256) {
        int i2 = idx >> 5, c = idx & 31;
        Wqkv2[idx]            = f16x2{(f16)Wq[(2 * i2) * D + c], (f16)Wq[(2 * i2 + 1) * D + c]};
        Wqkv2[512 + idx]      = f16x2{(f16)Wk[(2 * i2) * D + c], (f16)Wk[(2 * i2 + 1) * D + c]};
        Wqkv2[1024 + idx]     = f16x2{(f16)Wv[(2 * i2) * D + c], (f16)Wv[(2 * i2 + 1) * D + c]};
    }
    __syncthreads();
    int ln = threadIdx.x >> 5;
    int col = threadIdx.x & 31;
    float bc = b[col], bqc = bq[col], bkc = bk[col], bvc = bv[col];
    int head = col >> 3, d = col & 7, pr = head >> 1, hp = head & 1;
    for (int tile = blockIdx.x; tile < NTILE; tile += GS_GRID) {
        int node = tile * 8 + ln;
        float4 xr = ((const float4*)(x + (size_t)node * INF_))[col];
        ((f16x2*)xs[ln])[col * 2]     = f16x2{(f16)xr.x, (f16)xr.y};
        ((f16x2*)xs[ln])[col * 2 + 1] = f16x2{(f16)xr.z, (f16)xr.w};
        const f16x2* xrow = (const f16x2*)xs[ln];
        float acc = bc;
        #pragma unroll 16
        for (int i2 = 0; i2 < 64; ++i2)
            acc = __builtin_amdgcn_fdot2(xrow[i2], Ws2[i2 * D + col], acc, false);
        float hval = gelu_f(acc);
        h[(size_t)node * D + col] = hval;
        hsv[ln][col] = (f16)hval;
        const f16x2* hrow = (const f16x2*)hsv[ln];
        float aq = bqc, ak = bkc, av = bvc;
        #pragma unroll
        for (int i2 = 0; i2 < 16; ++i2) {
            f16x2 hx = hrow[i2];
            aq = __builtin_amdgcn_fdot2(hx, Wqkv2[i2 * D + col], aq, false);
            ak = __builtin_amdgcn_fdot2(hx, Wqkv2[512 + i2 * D + col], ak, false);
            av = __builtin_amdgcn_fdot2(hx, Wqkv2[1024 + i2 * D + col], av, false);
        }
        size_t qo = ((size_t)pr * NN + node) * 32;
        qv[qo + hp * 8 + d] = __float2half(aq);
        qv[qo + 16 + hp * 8 + d] = __float2half(av);
        kh[((size_t)pr * NN + node) * 16 + hp * 8 + d] = __float2half(ak);
    }
}

// pass C: LDS-staged bucket scatter (histogram -> scan -> cursor reservation ->
// LDS bucket-ordered stage -> coalesced copy-out). bkt16[pos] replaces the
// per-edge binary search in copy-out (1 LDS read vs 9-step serial search).
__global__ __launch_bounds__(256) void k_binC(const int* __restrict__ src,
        const int* __restrict__ dst, int* __restrict__ cur,
        unsigned int* __restrict__ tmp) {
    __shared__ int hist[NBKT];
    __shared__ int sc[512];
    __shared__ int gadj[NBKT];
    __shared__ unsigned int stage[EPB];        // 25 KB
    __shared__ unsigned short bkt16[EPB];      // 12.5 KB
    for (int i = threadIdx.x; i < NBKT; i += 256) hist[i] = 0;
    __syncthreads();
    int base = blockIdx.x * EPB;
    for (int i = threadIdx.x; i < EPB; i += 256)
        atomicAdd(&hist[dst[base + i] >> BSH], 1);
    __syncthreads();
    int t = threadIdx.x;
    sc[t]       = (t < NBKT) ? hist[t] : 0;
    sc[t + 256] = (t + 256 < NBKT) ? hist[t + 256] : 0;
    __syncthreads();
    for (int off = 1; off < 512; off <<= 1) {
        int a = (t >= off) ? sc[t - off] : 0;
        int b2 = sc[t + 256 - off];
        __syncthreads();
        sc[t] += a;
        sc[t + 256] += b2;
        __syncthreads();
    }
    for (int i = threadIdx.x; i < NBKT; i += 256) {
        int c = hist[i];
        int lb = sc[i] - c;
        hist[i] = lb;                          // placement cursor
        gadj[i] = c ? (atomicAdd(&cur[i], c) + i * RCAP - lb) : 0;
    }
    __syncthreads();
    for (int i = threadIdx.x; i < EPB; i += 256) {
        int d = dst[base + i];
        int bkt = d >> BSH;
        int pos = atomicAdd(&hist[bkt], 1);
        stage[pos] = (unsigned int)src[base + i]
                   | ((unsigned int)(d & (BNODES - 1)) << 17);
        bkt16[pos] = (unsigned short)bkt;
    }
    __syncthreads();
    for (int i = threadIdx.x; i < EPB; i += 256)
        tmp[gadj[bkt16[i]] + i] = stage[i];
}

// pass D: per-bucket LDS counting sort; emits rs/deg; streams full lines to csr.
__global__ __launch_bounds__(256) void k_binD(const unsigned int* __restrict__ tmp,
        const int* __restrict__ cur, int* __restrict__ csr,
        int* __restrict__ rs, int* __restrict__ deg) {
    __shared__ int lcnt[BNODES];
    __shared__ int lscan[BNODES];
    __shared__ int sorted[CAP];
    int b = blockIdx.x;
    int s0 = b * RCAP;
    int len = min(cur[b], RCAP);
    int s1 = s0 + len;
    lcnt[threadIdx.x] = 0;
    __syncthreads();
    for (int i = s0 + threadIdx.x; i < s1; i += 256)
        atomicAdd(&lcnt[tmp[i] >> 17], 1);
    __syncthreads();
    int v = lcnt[threadIdx.x];
    lscan[threadIdx.x] = v;
    __syncthreads();
    for (int off = 1; off < BNODES; off <<= 1) {
        int t = (threadIdx.x >= off) ? lscan[threadIdx.x - off] : 0;
        __syncthreads();
        lscan[threadIdx.x] += t;
        __syncthreads();
    }
    int excl = lscan[threadIdx.x] - v;
    int node = (b << BSH) + threadIdx.x;
    if (node < NN) {
        rs[node] = s0 + excl;
        deg[node] = v;
    }
    lcnt[threadIdx.x] = excl;
    __syncthreads();
    for (int i = s0 + threadIdx.x; i < s1; i += 256) {
        unsigned int p = tmp[i];
        int pos = atomicAdd(&lcnt[p >> 17], 1);
        sorted[pos] = (int)(p & 0x1FFFFu);
    }
    __syncthreads();
    for (int j = threadIdx.x; j < len; j += 256)
        csr[s0 + j] = sorted[j];
}

// attention: block = one head-PAIR x 8 nodes (4 waves x 2 nodes x (16 slots x 2 heads)).
// pair pinned to XCD half via blockIdx&7 -> per-XCD gather set = qv[pair] 6.4MB.
// 64B fused qv rows, fully consumed. (Measured floor: ~67us, FETCH ~197MB.)
__global__ __launch_bounds__(256) void k_attn(const __half* __restrict__ qv,
        const __half* __restrict__ kh,
        const int* __restrict__ rs, const int* __restrict__ deg,
        const int* __restrict__ csr, float* __restrict__ attnh) {
    int b = blockIdx.x;
    int pair = (b & 7) >> 2;                   // XCDs 0-3 -> pair0, 4-7 -> pair1
    int j = (b >> 3) * 4 + (b & 3);            // [0, 12500) per pair
    int lane = threadIdx.x & 63;
    int half = lane >> 5;
    int l5 = lane & 31;
    int slot = l5 >> 1, hp = l5 & 1;
    int node = j * 8 + (threadIdx.x >> 6) * 2 + half;   // < 100000 exact
    const __half* qvb = qv + (size_t)pair * NN * 32;
    union HF { float4 f4; __half2 h2[4]; };
    HF ku;
    ku.f4 = *(const float4*)(kh + ((size_t)pair * NN + node) * 16 + hp * 8);
    float kf[HD];
    #pragma unroll
    for (int i = 0; i < 4; ++i) {
        float2 t = __half22float2(ku.h2[i]);
        kf[2 * i] = t.x; kf[2 * i + 1] = t.y;
    }
    int start = rs[node], g = deg[node];
    int C = (g + 15) >> 4;
    int Cw = max(C, __shfl_xor(C, 32));        // loop bound uniform across wave
    float l = 0.f;
    float acc[HD];
    #pragma unroll
    for (int i = 0; i < HD; ++i) acc[i] = 0.f;

    bool act = slot < g;
    HF qu, vu;
    if (act) {
        int sn = csr[start + slot];
        const __half* r = qvb + (size_t)sn * 32;
        qu.f4 = *(const float4*)(r + hp * 8);
        vu.f4 = *(const float4*)(r + 16 + hp * 8);
    }
    for (int c = 1; c < Cw; ++c) {
        int idx2 = c * 16 + slot;
        bool act2 = idx2 < g;
        HF qu2, vu2;
        if (act2) {
            int sn2 = csr[start + idx2];
            const __half* r2 = qvb + (size_t)sn2 * 32;
            qu2.f4 = *(const float4*)(r2 + hp * 8);
            vu2.f4 = *(const float4*)(r2 + 16 + hp * 8);
        }
        if (act) {
            float s = 0.f;
            #pragma unroll
            for (int i = 0; i < 4; ++i) {
                float2 t = __half22float2(qu.h2[i]);
                s = fmaf(t.x, kf[2 * i], s);
                s = fmaf(t.y, kf[2 * i + 1], s);
            }
            float p = __expf(s * 0.35355339059327376f);
            l += p;
            #pragma unroll
            for (int i = 0; i < 4; ++i) {
                float2 t = __half22float2(vu.h2[i]);
                acc[2 * i] = fmaf(p, t.x, acc[2 * i]);
                acc[2 * i + 1] = fmaf(p, t.y, acc[2 * i + 1]);
            }
        }
        act = act2; qu = qu2; vu = vu2;
    }
    if (act) {
        float s = 0.f;
        #pragma unroll
        for (int i = 0; i < 4; ++i) {
            float2 t = __half22float2(qu.h2[i]);
            s = fmaf(t.x, kf[2 * i], s);
            s = fmaf(t.y, kf[2 * i + 1], s);
        }
        float p = __expf(s * 0.35355339059327376f);
        l += p;
        #pragma unroll
        for (int i = 0; i < 4; ++i) {
            float2 t = __half22float2(vu.h2[i]);
            acc[2 * i] = fmaf(p, t.x, acc[2 * i]);
            acc[2 * i + 1] = fmaf(p, t.y, acc[2 * i + 1]);
        }
    }
    #pragma unroll
    for (int off = 2; off < 32; off <<= 1) {
        l += __shfl_xor(l, off);
        #pragma unroll
        for (int i = 0; i < HD; ++i) acc[i] += __shfl_xor(acc[i], off);
    }
    if (slot == 0) {
        float inv = (l > 0.f) ? 1.0f / l : 0.f;
        float* outp = attnh + (size_t)node * D + (pair * 2 + hp) * HD;
        float4 o0 = { acc[0] * inv, acc[1] * inv, acc[2] * inv, acc[3] * inv };
        float4 o1 = { acc[4] * inv, acc[5] * inv, acc[6] * inv, acc[7] * inv };
        *(float4*)outp = o0;
        *(float4*)(outp + 4) = o1;
    }
}

// fused post-block (fdot2, grid-stride, barrier-free tile loop).
__global__ __launch_bounds__(256) void k_post(const float* __restrict__ attnh,
        const float* __restrict__ Wo, const float* __restrict__ bo,
        const float* __restrict__ W1, const float* __restrict__ b1,
        const float* __restrict__ W2, const float* __restrict__ b2,
        float* __restrict__ h,
        const float* __restrict__ Wqn, const float* __restrict__ bqn,
        const float* __restrict__ Wkn, const float* __restrict__ bkn,
        const float* __restrict__ Wvn, const float* __restrict__ bvn,
        __half* __restrict__ qv, __half* __restrict__ kh,
        const float* __restrict__ W_out, const float* __restrict__ b_out,
        float* __restrict__ outp) {
    __shared__ f16x2 Wos2[16 * D], W1s2[16 * D], W2s2[16 * D];  // 2 KB each
    __shared__ f16x2 Wqkv2[3 * 16 * D];                         // 6 KB
    __shared__ f16 as16[8][D], h1s16[8][D], ts16[8][D];         // 1.5 KB
    __shared__ float Wouts[D * 2];
    for (int idx = threadIdx.x; idx < 16 * D; idx += 256) {
        int i2 = idx >> 5, c = idx & 31;
        Wos2[idx] = f16x2{(f16)Wo[(2 * i2) * D + c], (f16)Wo[(2 * i2 + 1) * D + c]};
        W1s2[idx] = f16x2{(f16)W1[(2 * i2) * D + c], (f16)W1[(2 * i2 + 1) * D + c]};
        W2s2[idx] = f16x2{(f16)W2[(2 * i2) * D + c], (f16)W2[(2 * i2 + 1) * D + c]};
        if (Wqn) {
            Wqkv2[idx]        = f16x2{(f16)Wqn[(2 * i2) * D + c], (f16)Wqn[(2 * i2 + 1) * D + c]};
            Wqkv2[512 + idx]  = f16x2{(f16)Wkn[(2 * i2) * D + c], (f16)Wkn[(2 * i2 + 1) * D + c]};
            Wqkv2[1024 + idx] = f16x2{(f16)Wvn[(2 * i2) * D + c], (f16)Wvn[(2 * i2 + 1) * D + c]};
        }
    }
    if (outp && threadIdx.x < D * 2) Wouts[threadIdx.x] = W_out[threadIdx.x];
    __syncthreads();
    int ln = threadIdx.x >> 5, col = threadIdx.x & 31;
    float boc = bo[col], b1c = b1[col], b2c = b2[col];
    float bqc = 0.f, bkc = 0.f, bvc = 0.f;
    if (Wqn) { bqc = bqn[col]; bkc = bkn[col]; bvc = bvn[col]; }
    int head = col >> 3, d = col & 7, pr = head >> 1, hp = head & 1;
    for (int tile = blockIdx.x; tile < NTILE; tile += GS_GRID) {
        int node = tile * 8 + ln;
        as16[ln][col] = (f16)attnh[(size_t)node * D + col];
        float hv = h[(size_t)node * D + col];
        const f16x2* arow = (const f16x2*)as16[ln];
        float a = boc;
        #pragma unroll
        for (int i2 = 0; i2 < 16; ++i2)
            a = __builtin_amdgcn_fdot2(arow[i2], Wos2[i2 * D + col], a, false);
        float h1 = hv + a;
        h1s16[ln][col] = (f16)h1;
        const f16x2* h1row = (const f16x2*)h1s16[ln];
        float t = b1c;
        #pragma unroll
        for (int i2 = 0; i2 < 16; ++i2)
            t = __builtin_amdgcn_fdot2(h1row[i2], W1s2[i2 * D + col], t, false);
        ts16[ln][col] = (f16)gelu_f(t);
        const f16x2* trow = (const f16x2*)ts16[ln];
        float o = b2c;
        #pragma unroll
        for (int i2 = 0; i2 < 16; ++i2)
            o = __builtin_amdgcn_fdot2(trow[i2], W2s2[i2 * D + col], o, false);
        float hn = h1 + o;
        as16[ln][col] = (f16)hn;
        if (Wqn) {
            h[(size_t)node * D + col] = hn;
            const f16x2* hnrow = (const f16x2*)as16[ln];
            float aq = bqc, ak = bkc, av = bvc;
            #pragma unroll
            for (int i2 = 0; i2 < 16; ++i2) {
                f16x2 hx = hnrow[i2];
                aq = __builtin_amdgcn_fdot2(hx, Wqkv2[i2 * D + col], aq, false);
                ak = __builtin_amdgcn_fdot2(hx, Wqkv2[512 + i2 * D + col], ak, false);
                av = __builtin_amdgcn_fdot2(hx, Wqkv2[1024 + i2 * D + col], av, false);
            }
            size_t qo = ((size_t)pr * NN + node) * 32;
            qv[qo + hp * 8 + d] = __float2half(aq);
            qv[qo + 16 + hp * 8 + d] = __float2half(av);
            kh[((size_t)pr * NN + node) * 16 + hp * 8 + d] = __float2half(ak);
        }
        if (outp && col < 2) {
            float s = b_out[col];
            #pragma unroll
            for (int i = 0; i < D; ++i)
                s = fmaf((float)as16[ln][i], Wouts[i * 2 + col], s);
            outp[node * 2 + col] = s;
        }
    }
}

extern "C" void kernel_launch(void* const* d_in, const int* in_sizes, int n_in,
                              void* d_out, int out_size, void* d_ws, size_t ws_size,
                              hipStream_t stream) {
    const float* x     = (const float*)d_in[0];
    const int*   src   = (const int*)d_in[1];
    const int*   dst   = (const int*)d_in[2];
    const float* W_in  = (const float*)d_in[3];
    const float* b_in  = (const float*)d_in[4];
    const float* Wq    = (const float*)d_in[5];
    const float* bq    = (const float*)d_in[6];
    const float* Wk    = (const float*)d_in[7];
    const float* bk    = (const float*)d_in[8];
    const float* Wv    = (const float*)d_in[9];
    const float* bv    = (const float*)d_in[10];
    const float* Wo    = (const float*)d_in[11];
    const float* bo    = (const float*)d_in[12];
    const float* W1    = (const float*)d_in[13];
    const float* b1    = (const float*)d_in[14];
    const float* W2    = (const float*)d_in[15];
    const float* b2    = (const float*)d_in[16];
    const float* W_out = (const float*)d_in[17];
    const float* b_out = (const float*)d_in[18];
    float* out = (float*)d_out;

    char* w = (char*)d_ws;
    size_t off = 0;
    auto alloc = [&](size_t bytes) -> void* {
        void* p = w + off;
        off += (bytes + 255) & ~(size_t)255;
        return p;
    };
    float*  h     = (float*)alloc((size_t)NN * D * 4);
    __half* qv    = (__half*)alloc((size_t)NN * 2 * 32 * 2);  // 2 pairs x 32 halves
    __half* kh    = (__half*)alloc((size_t)NN * 2 * 16 * 2);  // 2 pairs x 16 halves
    float*  attnh = (float*)alloc((size_t)NN * D * 4);
    int* deg    = (int*)alloc((size_t)NN * 4);
    int* rs     = (int*)alloc((size_t)NN * 4);
    int* cur    = (int*)alloc((size_t)NBKT * 4);
    unsigned int* tmp = (unsigned int*)alloc((size_t)(NBKT + 1) * RCAP * 4);
    int* csr    = (int*)alloc((size_t)(NBKT + 1) * RCAP * 4);
    (void)ws_size; (void)in_sizes; (void)n_in; (void)out_size;

    k_in_proj_qkv<<<GS_GRID, 256, 0, stream>>>(x, W_in, b_in,
            Wq, bq, Wk, bk, Wv, bv, h, qv, kh, cur);
    k_binC<<<NBLK, 256, 0, stream>>>(src, dst, cur, tmp);
    k_binD<<<NBKT, 256, 0, stream>>>(tmp, cur, csr, rs, deg);

    // layer 0: attn + post (post also emits layer-1 q/k/v)
    k_attn<<<NN / 8 * 2, 256, 0, stream>>>(qv, kh, rs, deg, csr, attnh);
    k_post<<<GS_GRID, 256, 0, stream>>>(attnh, Wo, bo, W1, b1, W2, b2, h,
            Wq + D * D, bq + D, Wk + D * D, bk + D, Wv + D * D, bv + D,
            qv, kh, nullptr, nullptr, nullptr);
    // layer 1: attn + post (post emits final out)
    k_attn<<<NN / 8 * 2, 256, 0, stream>>>(qv, kh, rs, deg, csr, attnh);
    k_post<<<GS_GRID, 256, 0, stream>>>(attnh, Wo + D * D, bo + D,
            W1 + D * D, b1 + D, W2 + D * D, b2 + D, h,
            nullptr, nullptr, nullptr, nullptr, nullptr, nullptr,
            nullptr, nullptr, W_out, b_out, out);
}

// Round 18
// 273.843 us; speedup vs baseline: 1.1577x; 1.0048x over previous
//
#include <hip/hip_runtime.h>
#include <hip/hip_fp16.h>
#include <math.h>

#define NN 100000
#define NE 3200000
#define INF_ 128
#define D 32
#define H 4
#define HD 8

// binning config: bucket = dst >> 8 (256 dst nodes per bucket)
#define BSH 8
#define BNODES 256
#define NBKT 391                // ceil(100000/256)
#define NBLK 512                // chunking blocks for pass C
#define EPB (NE / NBLK)         // 6250 edges per block
#define CAP 12288               // LDS sorted capacity
#define RCAP 9216               // fixed region capacity (mean 8192, +11 sigma)
#define NTILE (NN / 8)          // 12500 node tiles of 8
#define GS_GRID 1250            // grid-stride blocks (10 tiles each)

typedef _Float16 f16;
typedef f16 __attribute__((ext_vector_type(2))) f16x2;

__device__ __forceinline__ float gelu_f(float x) {
    return 0.5f * x * (1.0f + erff(x * 0.70710678118654752f));
}

// qv layout: qv[pair][node][32] halves = {q_h0[8], q_h1[8], v_h0[8], v_h1[8]} (64B row)
// kh layout: kh[pair][node][16] halves = {k_h0[8], k_h1[8]} (32B row)

// layer0 fused: h = gelu(x @ W_in + b_in); q/k/v = h @ Wqkv + b (fp16 pair-packed).
__global__ __launch_bounds__(256) void k_in_proj_qkv(const float* __restrict__ x,
        const float* __restrict__ W, const float* __restrict__ b,
        const float* __restrict__ Wq, const float* __restrict__ bq,
        const float* __restrict__ Wk, const float* __restrict__ bk,
        const float* __restrict__ Wv, const float* __restrict__ bv,
        float* __restrict__ h, __half* __restrict__ qv, __half* __restrict__ kh,
        int* __restrict__ cur) {
    __shared__ f16x2 Ws2[64 * D];      // 8 KB
    __shared__ f16x2 Wqkv2[3 * 16 * D];// 6 KB
    __shared__ f16 xs[8][INF_];        // 2 KB
    __shared__ f16 hsv[8][D];          // 0.5 KB
    if (blockIdx.x == 0) {
        for (int i = threadIdx.x; i < NBKT; i += 256) cur[i] = 0;
    }
    for (int idx = threadIdx.x; idx < 64 * D; idx += 256) {
        int i2 = idx >> 5, c = idx & 31;
        Ws2[idx] = f16x2{(f16)W[(2 * i2) * D + c], (f16)W[(2 * i2 + 1) * D + c]};
    }
    for (int idx = threadIdx.x; idx < 16 * D; idx += 256) {
        int i2 = idx >> 5, c = idx & 31;
        Wqkv2[idx]            = f16x2{(f16)Wq[(2 * i2) * D + c], (f16)Wq[(2 * i2 + 1) * D + c]};
        Wqkv2[512 + idx]      = f16x2{(f16)Wk[(2 * i2) * D + c], (f16)Wk[(2 * i2 + 1) * D + c]};
        Wqkv2[1024 + idx]     = f16x2{(f16)Wv[(2 * i2) * D + c], (f16)Wv[(2 * i2 + 1) * D + c]};
    }
    __syncthreads();
    int ln = threadIdx.x >> 5;
    int col = threadIdx.x & 31;
    float bc = b[col], bqc = bq[col], bkc = bk[col], bvc = bv[col];
    int head = col >> 3, d = col & 7, pr = head >> 1, hp = head & 1;
    for (int tile = blockIdx.x; tile < NTILE; tile += GS_GRID) {
        int node = tile * 8 + ln;
        float4 xr = ((const float4*)(x + (size_t)node * INF_))[col];
        ((f16x2*)xs[ln])[col * 2]     = f16x2{(f16)xr.x, (f16)xr.y};
        ((f16x2*)xs[ln])[col * 2 + 1] = f16x2{(f16)xr.z, (f16)xr.w};
        const f16x2* xrow = (const f16x2*)xs[ln];
        float acc = bc;
        #pragma unroll 16
        for (int i2 = 0; i2 < 64; ++i2)
            acc = __builtin_amdgcn_fdot2(xrow[i2], Ws2[i2 * D + col], acc, false);
        float hval = gelu_f(acc);
        h[(size_t)node * D + col] = hval;
        hsv[ln][col] = (f16)hval;
        const f16x2* hrow = (const f16x2*)hsv[ln];
        float aq = bqc, ak = bkc, av = bvc;
        #pragma unroll
        for (int i2 = 0; i2 < 16; ++i2) {
            f16x2 hx = hrow[i2];
            aq = __builtin_amdgcn_fdot2(hx, Wqkv2[i2 * D + col], aq, false);
            ak = __builtin_amdgcn_fdot2(hx, Wqkv2[512 + i2 * D + col], ak, false);
            av = __builtin_amdgcn_fdot2(hx, Wqkv2[1024 + i2 * D + col], av, false);
        }
        size_t qo = ((size_t)pr * NN + node) * 32;
        qv[qo + hp * 8 + d] = __float2half(aq);
        qv[qo + 16 + hp * 8 + d] = __float2half(av);
        kh[((size_t)pr * NN + node) * 16 + hp * 8 + d] = __float2half(ak);
    }
}

// pass C: LDS-staged bucket scatter (histogram -> scan -> cursor reservation ->
// LDS bucket-ordered stage -> coalesced copy-out). bkt16[pos] replaces the
// per-edge binary search in copy-out (1 LDS read vs 9-step serial search).
__global__ __launch_bounds__(256) void k_binC(const int* __restrict__ src,
        const int* __restrict__ dst, int* __restrict__ cur,
        unsigned int* __restrict__ tmp) {
    __shared__ int hist[NBKT];
    __shared__ int sc[512];
    __shared__ int gadj[NBKT];
    __shared__ unsigned int stage[EPB];        // 25 KB
    __shared__ unsigned short bkt16[EPB];      // 12.5 KB
    for (int i = threadIdx.x; i < NBKT; i += 256) hist[i] = 0;
    __syncthreads();
    int base = blockIdx.x * EPB;
    for (int i = threadIdx.x; i < EPB; i += 256)
        atomicAdd(&hist[dst[base + i] >> BSH], 1);
    __syncthreads();
    int t = threadIdx.x;
    sc[t]       = (t < NBKT) ? hist[t] : 0;
    sc[t + 256] = (t + 256 < NBKT) ? hist[t + 256] : 0;
    __syncthreads();
    for (int off = 1; off < 512; off <<= 1) {
        int a = (t >= off) ? sc[t - off] : 0;
        int b2 = sc[t + 256 - off];
        __syncthreads();
        sc[t] += a;
        sc[t + 256] += b2;
        __syncthreads();
    }
    for (int i = threadIdx.x; i < NBKT; i += 256) {
        int c = hist[i];
        int lb = sc[i] - c;
        hist[i] = lb;                          // placement cursor
        gadj[i] = c ? (atomicAdd(&cur[i], c) + i * RCAP - lb) : 0;
    }
    __syncthreads();
    for (int i = threadIdx.x; i < EPB; i += 256) {
        int d = dst[base + i];
        int bkt = d >> BSH;
        int pos = atomicAdd(&hist[bkt], 1);
        stage[pos] = (unsigned int)src[base + i]
                   | ((unsigned int)(d & (BNODES - 1)) << 17);
        bkt16[pos] = (unsigned short)bkt;
    }
    __syncthreads();
    for (int i = threadIdx.x; i < EPB; i += 256)
        tmp[gadj[bkt16[i]] + i] = stage[i];
}

// pass D: per-bucket LDS counting sort; emits rs/deg; streams full lines to csr.
__global__ __launch_bounds__(256) void k_binD(const unsigned int* __restrict__ tmp,
        const int* __restrict__ cur, int* __restrict__ csr,
        int* __restrict__ rs, int* __restrict__ deg) {
    __shared__ int lcnt[BNODES];
    __shared__ int lscan[BNODES];
    __shared__ int sorted[CAP];
    int b = blockIdx.x;
    int s0 = b * RCAP;
    int len = min(cur[b], RCAP);
    int s1 = s0 + len;
    lcnt[threadIdx.x] = 0;
    __syncthreads();
    for (int i = s0 + threadIdx.x; i < s1; i += 256)
        atomicAdd(&lcnt[tmp[i] >> 17], 1);
    __syncthreads();
    int v = lcnt[threadIdx.x];
    lscan[threadIdx.x] = v;
    __syncthreads();
    for (int off = 1; off < BNODES; off <<= 1) {
        int t = (threadIdx.x >= off) ? lscan[threadIdx.x - off] : 0;
        __syncthreads();
        lscan[threadIdx.x] += t;
        __syncthreads();
    }
    int excl = lscan[threadIdx.x] - v;
    int node = (b << BSH) + threadIdx.x;
    if (node < NN) {
        rs[node] = s0 + excl;
        deg[node] = v;
    }
    lcnt[threadIdx.x] = excl;
    __syncthreads();
    for (int i = s0 + threadIdx.x; i < s1; i += 256) {
        unsigned int p = tmp[i];
        int pos = atomicAdd(&lcnt[p >> 17], 1);
        sorted[pos] = (int)(p & 0x1FFFFu);
    }
    __syncthreads();
    for (int j = threadIdx.x; j < len; j += 256)
        csr[s0 + j] = sorted[j];
}

// attention: block = one head-PAIR x 8 nodes (4 waves x 2 nodes x (16 slots x 2 heads)).
// pair pinned to XCD half via blockIdx&7 -> per-XCD gather set = qv[pair] 6.4MB.
// 64B fused qv rows, fully consumed. Score via fdot2 on f16 regs (saves
// 4 cvt + 8 fma per edge-lane; numerics proven in R13, absmax unchanged).
__global__ __launch_bounds__(256) void k_attn(const __half* __restrict__ qv,
        const __half* __restrict__ kh,
        const int* __restrict__ rs, const int* __restrict__ deg,
        const int* __restrict__ csr, float* __restrict__ attnh) {
    int b = blockIdx.x;
    int pair = (b & 7) >> 2;                   // XCDs 0-3 -> pair0, 4-7 -> pair1
    int j = (b >> 3) * 4 + (b & 3);            // [0, 12500) per pair
    int lane = threadIdx.x & 63;
    int half = lane >> 5;
    int l5 = lane & 31;
    int slot = l5 >> 1, hp = l5 & 1;
    int node = j * 8 + (threadIdx.x >> 6) * 2 + half;   // < 100000 exact
    const __half* qvb = qv + (size_t)pair * NN * 32;
    union HF { float4 f4; f16x2 p[4]; __half2 h2[4]; };
    HF ku;
    ku.f4 = *(const float4*)(kh + ((size_t)pair * NN + node) * 16 + hp * 8);
    int start = rs[node], g = deg[node];
    int C = (g + 15) >> 4;
    int Cw = max(C, __shfl_xor(C, 32));        // loop bound uniform across wave
    float l = 0.f;
    float acc[HD];
    #pragma unroll
    for (int i = 0; i < HD; ++i) acc[i] = 0.f;

    bool act = slot < g;
    HF qu, vu;
    if (act) {
        int sn = csr[start + slot];
        const __half* r = qvb + (size_t)sn * 32;
        qu.f4 = *(const float4*)(r + hp * 8);
        vu.f4 = *(const float4*)(r + 16 + hp * 8);
    }
    for (int c = 1; c < Cw; ++c) {
        int idx2 = c * 16 + slot;
        bool act2 = idx2 < g;
        HF qu2, vu2;
        if (act2) {
            int sn2 = csr[start + idx2];
            const __half* r2 = qvb + (size_t)sn2 * 32;
            qu2.f4 = *(const float4*)(r2 + hp * 8);
            vu2.f4 = *(const float4*)(r2 + 16 + hp * 8);
        }
        if (act) {
            float s = 0.f;
            #pragma unroll
            for (int i = 0; i < 4; ++i)
                s = __builtin_amdgcn_fdot2(qu.p[i], ku.p[i], s, false);
            float p = __expf(s * 0.35355339059327376f);
            l += p;
            #pragma unroll
            for (int i = 0; i < 4; ++i) {
                float2 t = __half22float2(vu.h2[i]);
                acc[2 * i] = fmaf(p, t.x, acc[2 * i]);
                acc[2 * i + 1] = fmaf(p, t.y, acc[2 * i + 1]);
            }
        }
        act = act2; qu = qu2; vu = vu2;
    }
    if (act) {
        float s = 0.f;
        #pragma unroll
        for (int i = 0; i < 4; ++i)
            s = __builtin_amdgcn_fdot2(qu.p[i], ku.p[i], s, false);
        float p = __expf(s * 0.35355339059327376f);
        l += p;
        #pragma unroll
        for (int i = 0; i < 4; ++i) {
            float2 t = __half22float2(vu.h2[i]);
            acc[2 * i] = fmaf(p, t.x, acc[2 * i]);
            acc[2 * i + 1] = fmaf(p, t.y, acc[2 * i + 1]);
        }
    }
    #pragma unroll
    for (int off = 2; off < 32; off <<= 1) {
        l += __shfl_xor(l, off);
        #pragma unroll
        for (int i = 0; i < HD; ++i) acc[i] += __shfl_xor(acc[i], off);
    }
    if (slot == 0) {
        float inv = (l > 0.f) ? 1.0f / l : 0.f;
        float* outp = attnh + (size_t)node * D + (pair * 2 + hp) * HD;
        float4 o0 = { acc[0] * inv, acc[1] * inv, acc[2] * inv, acc[3] * inv };
        float4 o1 = { acc[4] * inv, acc[5] * inv, acc[6] * inv, acc[7] * inv };
        *(float4*)outp = o0;
        *(float4*)(outp + 4) = o1;
    }
}

// fused post-block (fdot2, grid-stride, barrier-free tile loop).
__global__ __launch_bounds__(256) void k_post(const float* __restrict__ attnh,
        const float* __restrict__ Wo, const float* __restrict__ bo,
        const float* __restrict__ W1, const float* __restrict__ b1,
        const float* __restrict__ W2, const float* __restrict__ b2,
        float* __restrict__ h,
        const float* __restrict__ Wqn, const float* __restrict__ bqn,
        const float* __restrict__ Wkn, const float* __restrict__ bkn,
        const float* __restrict__ Wvn, const float* __restrict__ bvn,
        __half* __restrict__ qv, __half* __restrict__ kh,
        const float* __restrict__ W_out, const float* __restrict__ b_out,
        float* __restrict__ outp) {
    __shared__ f16x2 Wos2[16 * D], W1s2[16 * D], W2s2[16 * D];  // 2 KB each
    __shared__ f16x2 Wqkv2[3 * 16 * D];                         // 6 KB
    __shared__ f16 as16[8][D], h1s16[8][D], ts16[8][D];         // 1.5 KB
    __shared__ float Wouts[D * 2];
    for (int idx = threadIdx.x; idx < 16 * D; idx += 256) {
        int i2 = idx >> 5, c = idx & 31;
        Wos2[idx] = f16x2{(f16)Wo[(2 * i2) * D + c], (f16)Wo[(2 * i2 + 1) * D + c]};
        W1s2[idx] = f16x2{(f16)W1[(2 * i2) * D + c], (f16)W1[(2 * i2 + 1) * D + c]};
        W2s2[idx] = f16x2{(f16)W2[(2 * i2) * D + c], (f16)W2[(2 * i2 + 1) * D + c]};
        if (Wqn) {
            Wqkv2[idx]        = f16x2{(f16)Wqn[(2 * i2) * D + c], (f16)Wqn[(2 * i2 + 1) * D + c]};
            Wqkv2[512 + idx]  = f16x2{(f16)Wkn[(2 * i2) * D + c], (f16)Wkn[(2 * i2 + 1) * D + c]};
            Wqkv2[1024 + idx] = f16x2{(f16)Wvn[(2 * i2) * D + c], (f16)Wvn[(2 * i2 + 1) * D + c]};
        }
    }
    if (outp && threadIdx.x < D * 2) Wouts[threadIdx.x] = W_out[threadIdx.x];
    __syncthreads();
    int ln = threadIdx.x >> 5, col = threadIdx.x & 31;
    float boc = bo[col], b1c = b1[col], b2c = b2[col];
    float bqc = 0.f, bkc = 0.f, bvc = 0.f;
    if (Wqn) { bqc = bqn[col]; bkc = bkn[col]; bvc = bvn[col]; }
    int head = col >> 3, d = col & 7, pr = head >> 1, hp = head & 1;
    for (int tile = blockIdx.x; tile < NTILE; tile += GS_GRID) {
        int node = tile * 8 + ln;
        as16[ln][col] = (f16)attnh[(size_t)node * D + col];
        float hv = h[(size_t)node * D + col];
        const f16x2* arow = (const f16x2*)as16[ln];
        float a = boc;
        #pragma unroll
        for (int i2 = 0; i2 < 16; ++i2)
            a = __builtin_amdgcn_fdot2(arow[i2], Wos2[i2 * D + col], a, false);
        float h1 = hv + a;
        h1s16[ln][col] = (f16)h1;
        const f16x2* h1row = (const f16x2*)h1s16[ln];
        float t = b1c;
        #pragma unroll
        for (int i2 = 0; i2 < 16; ++i2)
            t = __builtin_amdgcn_fdot2(h1row[i2], W1s2[i2 * D + col], t, false);
        ts16[ln][col] = (f16)gelu_f(t);
        const f16x2* trow = (const f16x2*)ts16[ln];
        float o = b2c;
        #pragma unroll
        for (int i2 = 0; i2 < 16; ++i2)
            o = __builtin_amdgcn_fdot2(trow[i2], W2s2[i2 * D + col], o, false);
        float hn = h1 + o;
        as16[ln][col] = (f16)hn;
        if (Wqn) {
            h[(size_t)node * D + col] = hn;
            const f16x2* hnrow = (const f16x2*)as16[ln];
            float aq = bqc, ak = bkc, av = bvc;
            #pragma unroll
            for (int i2 = 0; i2 < 16; ++i2) {
                f16x2 hx = hnrow[i2];
                aq = __builtin_amdgcn_fdot2(hx, Wqkv2[i2 * D + col], aq, false);
                ak = __builtin_amdgcn_fdot2(hx, Wqkv2[512 + i2 * D + col], ak, false);
                av = __builtin_amdgcn_fdot2(hx, Wqkv2[1024 + i2 * D + col], av, false);
            }
            size_t qo = ((size_t)pr * NN + node) * 32;
            qv[qo + hp * 8 + d] = __float2half(aq);
            qv[qo + 16 + hp * 8 + d] = __float2half(av);
            kh[((size_t)pr * NN + node) * 16 + hp * 8 + d] = __float2half(ak);
        }
        if (outp && col < 2) {
            float s = b_out[col];
            #pragma unroll
            for (int i = 0; i < D; ++i)
                s = fmaf((float)as16[ln][i], Wouts[i * 2 + col], s);
            outp[node * 2 + col] = s;
        }
    }
}

extern "C" void kernel_launch(void* const* d_in, const int* in_sizes, int n_in,
                              void* d_out, int out_size, void* d_ws, size_t ws_size,
                              hipStream_t stream) {
    const float* x     = (const float*)d_in[0];
    const int*   src   = (const int*)d_in[1];
    const int*   dst   = (const int*)d_in[2];
    const float* W_in  = (const float*)d_in[3];
    const float* b_in  = (const float*)d_in[4];
    const float* Wq    = (const float*)d_in[5];
    const float* bq    = (const float*)d_in[6];
    const float* Wk    = (const float*)d_in[7];
    const float* bk    = (const float*)d_in[8];
    const float* Wv    = (const float*)d_in[9];
    const float* bv    = (const float*)d_in[10];
    const float* Wo    = (const float*)d_in[11];
    const float* bo    = (const float*)d_in[12];
    const float* W1    = (const float*)d_in[13];
    const float* b1    = (const float*)d_in[14];
    const float* W2    = (const float*)d_in[15];
    const float* b2    = (const float*)d_in[16];
    const float* W_out = (const float*)d_in[17];
    const float* b_out = (const float*)d_in[18];
    float* out = (float*)d_out;

    char* w = (char*)d_ws;
    size_t off = 0;
    auto alloc = [&](size_t bytes) -> void* {
        void* p = w + off;
        off += (bytes + 255) & ~(size_t)255;
        return p;
    };
    float*  h     = (float*)alloc((size_t)NN * D * 4);
    __half* qv    = (__half*)alloc((size_t)NN * 2 * 32 * 2);  // 2 pairs x 32 halves
    __half* kh    = (__half*)alloc((size_t)NN * 2 * 16 * 2);  // 2 pairs x 16 halves
    float*  attnh = (float*)alloc((size_t)NN * D * 4);
    int* deg    = (int*)alloc((size_t)NN * 4);
    int* rs     = (int*)alloc((size_t)NN * 4);
    int* cur    = (int*)alloc((size_t)NBKT * 4);
    unsigned int* tmp = (unsigned int*)alloc((size_t)(NBKT + 1) * RCAP * 4);
    int* csr    = (int*)alloc((size_t)(NBKT + 1) * RCAP * 4);
    (void)ws_size; (void)in_sizes; (void)n_in; (void)out_size;

    k_in_proj_qkv<<<GS_GRID, 256, 0, stream>>>(x, W_in, b_in,
            Wq, bq, Wk, bk, Wv, bv, h, qv, kh, cur);
    k_binC<<<NBLK, 256, 0, stream>>>(src, dst, cur, tmp);
    k_binD<<<NBKT, 256, 0, stream>>>(tmp, cur, csr, rs, deg);

    // layer 0: attn + post (post also emits layer-1 q/k/v)
    k_attn<<<NN / 8 * 2, 256, 0, stream>>>(qv, kh, rs, deg, csr, attnh);
    k_post<<<GS_GRID, 256, 0, stream>>>(attnh, Wo, bo, W1, b1, W2, b2, h,
            Wq + D * D, bq + D, Wk + D * D, bk + D, Wv + D * D, bv + D,
            qv, kh, nullptr, nullptr, nullptr);
    // layer 1: attn + post (post emits final out)
    k_attn<<<NN / 8 * 2, 256, 0, stream>>>(qv, kh, rs, deg, csr, attnh);
    k_post<<<GS_GRID, 256, 0, stream>>>(attnh, Wo + D * D, bo + D,
            W1 + D * D, b1 + D, W2 + D * D, b2 + D, h,
            nullptr, nullptr, nullptr, nullptr, nullptr, nullptr,
            nullptr, nullptr, W_out, b_out, out);
}